// Round 15
// baseline (197.024 us; speedup 1.0000x reference)
//
#include <hip/hip_runtime.h>
#include <hip/hip_fp16.h>
#include <math.h>

#define THREADS 256
#define NPB 512           // nodes per bin
#define SHIFT 9
#define MASK 511
#define MAX_BINS 256
#define CAPE 20480        // per-bin capacity (mu=16.3k, +8 sigma, +3*512 align pad)
#define BIN_BLOCKS 512

// ===================== stage 1: bin edges by target>>9 =======================
// R15: two-read low-LDS variant. Pass A: int4 load + LDS histogram only (no
// stash). Pass B: re-read row/col (L2-warm, same block), recompute bin, LDS
// counting-sort scatter into sbuf2. Pass C: wave-per-bin coalesced flush
// (R12-proven). Dyn LDS 56KB -> 25KB: occupancy 2 -> 6 blocks/CU for the
// latency-bound LDS-atomic passes.

__global__ void __launch_bounds__(256) k_bin(const int* __restrict__ row,
                                             const int* __restrict__ col,
                                             int e, int* __restrict__ binCnt,
                                             int* __restrict__ binned) {
    __shared__ int hist[MAX_BINS];
    __shared__ int cur[MAX_BINS];
    __shared__ int baseg[MAX_BINS];
    __shared__ int lofs[MAX_BINS];
    __shared__ int scn[MAX_BINS];
    extern __shared__ int sbuf2[];  // packed, bin-sorted
    int per = (((e + (int)gridDim.x - 1) / (int)gridDim.x) + 3) & ~3;
    int e0 = blockIdx.x * per;
    if (e0 >= e) return;
    int e1 = min(e0 + per, e);
    int cntL = e1 - e0;
    int tid = threadIdx.x;
    hist[tid] = 0; cur[tid] = 0;
    __syncthreads();
    int nq = cntL >> 2;
    const int4* c4 = (const int4*)(col + e0);
    // pass A: histogram only
    for (int q = tid; q < nq; q += 256) {
        int4 c = c4[q];
        atomicAdd(&hist[c.x >> SHIFT], 1);
        atomicAdd(&hist[c.y >> SHIFT], 1);
        atomicAdd(&hist[c.z >> SHIFT], 1);
        atomicAdd(&hist[c.w >> SHIFT], 1);
    }
    for (int li = (nq << 2) + tid; li < cntL; li += 256)
        atomicAdd(&hist[col[e0 + li] >> SHIFT], 1);
    __syncthreads();
    {
        int h = hist[tid];
        baseg[tid] = (h > 0) ? atomicAdd(&binCnt[tid], h) : 0;
        scn[tid] = h;
    }
    __syncthreads();
    for (int off = 1; off < MAX_BINS; off <<= 1) {
        int a = (tid >= off) ? scn[tid - off] : 0;
        __syncthreads();
        scn[tid] += a;
        __syncthreads();
    }
    lofs[tid] = scn[tid] - hist[tid];
    __syncthreads();
    // pass B: re-read (L2-warm) + LDS counting-sort scatter
    const int4* r4 = (const int4*)(row + e0);
    for (int q = tid; q < nq; q += 256) {
        int4 r = r4[q], c = c4[q];
        int b, p;
        b = c.x >> SHIFT; p = lofs[b] + atomicAdd(&cur[b], 1);
        sbuf2[p] = (r.x << SHIFT) | (c.x & MASK);
        b = c.y >> SHIFT; p = lofs[b] + atomicAdd(&cur[b], 1);
        sbuf2[p] = (r.y << SHIFT) | (c.y & MASK);
        b = c.z >> SHIFT; p = lofs[b] + atomicAdd(&cur[b], 1);
        sbuf2[p] = (r.z << SHIFT) | (c.z & MASK);
        b = c.w >> SHIFT; p = lofs[b] + atomicAdd(&cur[b], 1);
        sbuf2[p] = (r.w << SHIFT) | (c.w & MASK);
    }
    for (int li = (nq << 2) + tid; li < cntL; li += 256) {
        int c = col[e0 + li], r = row[e0 + li];
        int b = c >> SHIFT;
        int p = lofs[b] + atomicAdd(&cur[b], 1);
        sbuf2[p] = (r << SHIFT) | (c & MASK);
    }
    __syncthreads();
    // pass C: wave-per-bin coalesced flush
    int wv = tid >> 6, ln = tid & 63;
    for (int b = wv; b < MAX_BINS; b += 4) {
        int len = hist[b];
        int lo = lofs[b];
        int gb = baseg[b];
        for (int i = ln; i < len; i += 64) {
            int pos = gb + i;
            if (pos < CAPE) binned[b * CAPE + pos] = sbuf2[lo + i];
        }
    }
}

// ======= stage 2: per-bin counting sort -> CSR + deg + ptr + dinv ============
// One 512-node bin per block; degrees PADDED to multiples of 4 in the scan so
// every node's csr segment is 16B-aligned (enables int4 csr loads in gather1).

__global__ void __launch_bounds__(512) k_sort(const int* __restrict__ binned,
                                              const int* __restrict__ binCnt,
                                              int* __restrict__ csr,
                                              int* __restrict__ gptr,
                                              int* __restrict__ gcnt,
                                              float* __restrict__ dinv, int n) {
    __shared__ int cnt[NPB];
    __shared__ int scn[NPB];
    int b = blockIdx.x;
    int t = threadIdx.x;
    cnt[t] = 0;
    __syncthreads();
    int m = min(binCnt[b], CAPE);
    const int* eb = binned + b * CAPE;
    for (int i = t; i < m; i += 512)
        atomicAdd(&cnt[eb[i] & MASK], 1);
    __syncthreads();
    int v = cnt[t];
    int pv = (v + 3) & ~3;  // 4-aligned degree for csr segment alignment
    scn[t] = pv;
    __syncthreads();
    for (int off = 1; off < NPB; off <<= 1) {
        int a = (t >= off) ? scn[t - off] : 0;
        __syncthreads();
        scn[t] += a;
        __syncthreads();
    }
    int excl = scn[t] - pv;  // multiple of 4
    int node = b * NPB + t;
    if (node < n) {
        gptr[node] = b * CAPE + excl;
        gcnt[node] = v;
        dinv[node] = rsqrtf((float)(v + 1));
    }
    cnt[t] = excl;  // reuse as cursor
    __syncthreads();
    for (int i = t; i < m; i += 512) {
        int e = eb[i];
        int slot = atomicAdd(&cnt[e & MASK], 1);
        if (slot < CAPE) csr[b * CAPE + slot] = e >> SHIFT;
    }
}

// --- z1h[i] = fp16( dinv[i] * (x[i] @ W1) ), LDS-staged x --------------------
__global__ void __launch_bounds__(256) k_xform1(const float* __restrict__ x,
                                                const float* __restrict__ W1,
                                                const float* __restrict__ dinv,
                                                __half* __restrict__ z1h, int n) {
    __shared__ float sW[25 * 16];
    __shared__ float tile[4][64 * 25];
    int w = threadIdx.x >> 6, lane = threadIdx.x & 63;
    for (int t = threadIdx.x; t < 25 * 16; t += 256) sW[t] = W1[t];
    long blockRow = (long)blockIdx.x * 256;
    long waveRow = blockRow + w * 64;
    const float* src = x + waveRow * 25;
    long rem = (long)n * 25 - waveRow * 25;
#pragma unroll
    for (int k = 0; k < 25; k++) {
        int idx = k * 64 + lane;
        tile[w][idx] = (idx < rem) ? src[idx] : 0.f;
    }
    __syncthreads();
    long node = blockRow + threadIdx.x;
    if (node >= n) return;
    float xi[25];
#pragma unroll
    for (int k = 0; k < 25; k++) xi[k] = tile[w][lane * 25 + k];
    float di = dinv[node];
    union { int4 v[2]; __half h[16]; } u;
#pragma unroll
    for (int c = 0; c < 16; c++) {
        float a = 0.f;
#pragma unroll
        for (int k = 0; k < 25; k++) a = fmaf(xi[k], sW[k * 16 + c], a);
        u.h[c] = __float2half(a * di);
    }
    int4* o = (int4*)(z1h + node * 16);
    o[0] = u.v[0];
    o[1] = u.v[1];
}

// --- gather layer 1 + bias/relu + @W2: 8 lanes/node, half2 loads, ------------
// int4 csr loads (csr segments 16B-aligned by k_sort's padded scan).
__global__ void k_gather1(const int* __restrict__ ptr, const int* __restrict__ cnt,
                          const int* __restrict__ csr, const __half* __restrict__ z1h,
                          const float* __restrict__ dinv,
                          const float* __restrict__ b1, const float* __restrict__ W2,
                          __half2* __restrict__ z2h, int n) {
    int g = threadIdx.x >> 3;
    int c2 = threadIdx.x & 7;
    int node = blockIdx.x * 32 + g;
    if (node >= n) return;
    const __half2* z1p = (const __half2*)z1h;
    int beg = ptr[node], d = cnt[node];
    __half2 sv = z1p[(size_t)node * 8 + c2];
    float a0 = __low2float(sv), a1 = __high2float(sv);
    int e = 0;
    for (; e + 4 <= d; e += 4) {
        int4 s = *(const int4*)(csr + beg + e);  // aligned: beg%4==0, e%4==0
        __half2 v0 = z1p[(size_t)s.x * 8 + c2];
        __half2 v1 = z1p[(size_t)s.y * 8 + c2];
        __half2 v2 = z1p[(size_t)s.z * 8 + c2];
        __half2 v3 = z1p[(size_t)s.w * 8 + c2];
        a0 += (__low2float(v0) + __low2float(v1)) + (__low2float(v2) + __low2float(v3));
        a1 += (__high2float(v0) + __high2float(v1)) + (__high2float(v2) + __high2float(v3));
    }
    for (; e < d; e++) {
        __half2 v = z1p[(size_t)csr[beg + e] * 8 + c2];
        a0 += __low2float(v);
        a1 += __high2float(v);
    }
    float di = dinv[node];
    int cA = c2 * 2, cB = c2 * 2 + 1;
    float hA = fmaxf(fmaf(di, a0, b1[cA]), 0.f);
    float hB = fmaxf(fmaf(di, a1, b1[cB]), 0.f);
    float p0 = hA * W2[cA * 2 + 0] + hB * W2[cB * 2 + 0];
    float p1 = hA * W2[cA * 2 + 1] + hB * W2[cB * 2 + 1];
#pragma unroll
    for (int m = 1; m < 8; m <<= 1) {
        p0 += __shfl_xor(p0, m, 8);
        p1 += __shfl_xor(p1, m, 8);
    }
    if (c2 == 0) z2h[node] = __floats2half2_rn(di * p0, di * p1);
}

// --- gather layer 2: 8 lanes/node + bias + log_softmax(2) --------------------
__global__ void k_gather2(const int* __restrict__ ptr, const int* __restrict__ cnt,
                          const int* __restrict__ csr, const __half2* __restrict__ z2h,
                          const float* __restrict__ dinv,
                          const float* __restrict__ b2, float* __restrict__ out, int n) {
    int g = threadIdx.x >> 3;
    int c = threadIdx.x & 7;
    int node = blockIdx.x * 32 + g;
    if (node >= n) return;
    int beg = ptr[node], d = cnt[node];
    float a0 = 0.f, a1 = 0.f;
    for (int e = c; e < d; e += 8) {
        __half2 v = z2h[csr[beg + e]];
        a0 += __low2float(v);
        a1 += __high2float(v);
    }
#pragma unroll
    for (int m = 1; m < 8; m <<= 1) {
        a0 += __shfl_xor(a0, m, 8);
        a1 += __shfl_xor(a1, m, 8);
    }
    if (c == 0) {
        __half2 self = z2h[node];
        a0 += __low2float(self);
        a1 += __high2float(self);
        float di = dinv[node];
        float h0 = fmaf(di, a0, b2[0]);
        float h1 = fmaf(di, a1, b2[1]);
        float mx = fmaxf(h0, h1);
        float lse = mx + log1pf(expf(fminf(h0, h1) - mx));
        ((float2*)out)[node] = make_float2(h0 - lse, h1 - lse);
    }
}

// ===================== fallback: round-2 CSR pipeline ========================

__global__ void k_zero(int* cnt, int n) {
    int i = blockIdx.x * blockDim.x + threadIdx.x;
    if (i < n) cnt[i] = 0;
}

__global__ void k_count_pos(const int* __restrict__ col, int e,
                            int* __restrict__ cnt, int* __restrict__ pos) {
    int i = blockIdx.x * blockDim.x + threadIdx.x;
    if (i < e) pos[i] = atomicAdd(&cnt[col[i]], 1);
}

__global__ void k_scan1(const int* __restrict__ cnt, int n,
                        int* __restrict__ excl, int* __restrict__ bsum) {
    __shared__ int s[256];
    int i = blockIdx.x * 256 + threadIdx.x;
    int v = (i < n) ? cnt[i] : 0;
    s[threadIdx.x] = v;
    __syncthreads();
    for (int off = 1; off < 256; off <<= 1) {
        int t = (threadIdx.x >= off) ? s[threadIdx.x - off] : 0;
        __syncthreads();
        s[threadIdx.x] += t;
        __syncthreads();
    }
    if (i < n) excl[i] = s[threadIdx.x] - v;
    if (threadIdx.x == 255) bsum[blockIdx.x] = s[255];
}

__global__ void k_scan2(int* __restrict__ bsum, int nb) {
    __shared__ int s[1024];
    int v = (threadIdx.x < nb) ? bsum[threadIdx.x] : 0;
    s[threadIdx.x] = v;
    __syncthreads();
    for (int off = 1; off < 1024; off <<= 1) {
        int t = (threadIdx.x >= off) ? s[threadIdx.x - off] : 0;
        __syncthreads();
        s[threadIdx.x] += t;
        __syncthreads();
    }
    if (threadIdx.x < nb) bsum[threadIdx.x] = s[threadIdx.x] - v;
}

__global__ void k_scan3(int* __restrict__ excl, const int* __restrict__ boff, int n) {
    int i = blockIdx.x * 256 + threadIdx.x;
    if (i < n) excl[i] += boff[blockIdx.x];
}

__global__ void k_place(const int* __restrict__ row, const int* __restrict__ col,
                        const int* __restrict__ pos, const int* __restrict__ ptr,
                        int e, int* __restrict__ csr) {
    int i = blockIdx.x * blockDim.x + threadIdx.x;
    if (i >= e) return;
    csr[ptr[col[i]] + pos[i]] = row[i];
}

__global__ void k_dinv_from_cnt(const int* __restrict__ cnt, float* __restrict__ dinv, int n) {
    int i = blockIdx.x * blockDim.x + threadIdx.x;
    if (i < n) dinv[i] = rsqrtf((float)(cnt[i] + 1));
}

__global__ void k_gather1_fb(const int* __restrict__ ptr, const int* __restrict__ cnt,
                             const int* __restrict__ csr, const __half* __restrict__ z1h,
                             const float* __restrict__ dinv,
                             const float* __restrict__ b1, const float* __restrict__ W2,
                             __half2* __restrict__ z2h, int n) {
    int g = threadIdx.x >> 3;
    int c2 = threadIdx.x & 7;
    int node = blockIdx.x * 32 + g;
    if (node >= n) return;
    const __half2* z1p = (const __half2*)z1h;
    int beg = ptr[node], d = cnt[node];
    __half2 sv = z1p[(size_t)node * 8 + c2];
    float a0 = __low2float(sv), a1 = __high2float(sv);
    for (int e = 0; e < d; e++) {
        __half2 v = z1p[(size_t)csr[beg + e] * 8 + c2];
        a0 += __low2float(v);
        a1 += __high2float(v);
    }
    float di = dinv[node];
    int cA = c2 * 2, cB = c2 * 2 + 1;
    float hA = fmaxf(fmaf(di, a0, b1[cA]), 0.f);
    float hB = fmaxf(fmaf(di, a1, b1[cB]), 0.f);
    float p0 = hA * W2[cA * 2 + 0] + hB * W2[cB * 2 + 0];
    float p1 = hA * W2[cA * 2 + 1] + hB * W2[cB * 2 + 1];
#pragma unroll
    for (int m = 1; m < 8; m <<= 1) {
        p0 += __shfl_xor(p0, m, 8);
        p1 += __shfl_xor(p1, m, 8);
    }
    if (c2 == 0) z2h[node] = __floats2half2_rn(di * p0, di * p1);
}

// ============================== host launcher ================================

extern "C" void kernel_launch(void* const* d_in, const int* in_sizes, int n_in,
                              void* d_out, int out_size, void* d_ws, size_t ws_size,
                              hipStream_t stream) {
    const float* x  = (const float*)d_in[0];
    const int*   ei = (const int*)d_in[1];
    const float* W1 = (const float*)d_in[2];
    const float* b1 = (const float*)d_in[3];
    const float* W2 = (const float*)d_in[4];
    const float* b2 = (const float*)d_in[5];
    float* out = (float*)d_out;

    const int N = in_sizes[0] / 25;
    const int E = in_sizes[1] / 2;
    const int* row = ei;
    const int* col = ei + E;

    const int nbins = (N + NPB - 1) / NPB;
    const int gN = (N + THREADS - 1) / THREADS;
    const int gE = (E + THREADS - 1) / THREADS;

    size_t off = 0;
    auto take = [&](size_t bytes) { size_t o = off; off = (off + bytes + 255) & ~(size_t)255; return o; };
    size_t o_binCnt = take(MAX_BINS * sizeof(int));
    size_t o_binned = take((size_t)nbins * CAPE * sizeof(int));
    size_t o_csr    = take((size_t)nbins * CAPE * sizeof(int));
    size_t o_ptr    = take((size_t)N * sizeof(int));
    size_t o_cnt    = take((size_t)N * sizeof(int));
    size_t o_dinv   = take((size_t)N * sizeof(float));
    size_t o_z1h    = take((size_t)N * 16 * sizeof(__half));
    size_t o_z2h    = take((size_t)N * sizeof(__half2));
    size_t need_v15 = off;

    // bin load: mu = E/nbins, sigma = sqrt(mu); csr needs +3*NPB alignment pad
    double mu = (double)E / (double)nbins;
    bool cap_ok = (mu + 8.0 * sqrt(mu) + 3.0 * NPB) < (double)CAPE;
    const int per = (((E + BIN_BLOCKS - 1) / BIN_BLOCKS) + 3) & ~3;
    size_t dynLds = (size_t)per * 4 + 64;  // sbuf2 only (R15 low-LDS k_bin)
    bool lds_ok = dynLds <= 60 * 1024;
    bool use_v15 = (nbins <= MAX_BINS) && (ws_size >= need_v15) &&
                   (N <= NPB * MAX_BINS) && cap_ok && lds_ok;

    char* wsb = (char*)d_ws;
    if (use_v15) {
        int*     binCnt = (int*)(wsb + o_binCnt);
        int*     binned = (int*)(wsb + o_binned);
        int*     csr    = (int*)(wsb + o_csr);
        int*     ptr    = (int*)(wsb + o_ptr);
        int*     cnt    = (int*)(wsb + o_cnt);
        float*   dinv   = (float*)(wsb + o_dinv);
        __half*  z1h    = (__half*)(wsb + o_z1h);
        __half2* z2h    = (__half2*)(wsb + o_z2h);

        hipMemsetAsync(binCnt, 0, MAX_BINS * sizeof(int), stream);
        k_bin<<<BIN_BLOCKS, 256, dynLds, stream>>>(row, col, E, binCnt, binned);
        k_sort<<<nbins, 512, 0, stream>>>(binned, binCnt, csr, ptr, cnt, dinv, N);
        k_xform1<<<gN, 256, 0, stream>>>(x, W1, dinv, z1h, N);
        k_gather1<<<(N + 31) / 32, 256, 0, stream>>>(ptr, cnt, csr, z1h, dinv, b1, W2, z2h, N);
        k_gather2<<<(N + 31) / 32, 256, 0, stream>>>(ptr, cnt, csr, z2h, dinv, b2, out, N);
    } else {
        char* w = wsb;
        int*     cnt  = (int*)w;     w += (size_t)N * sizeof(int);
        int*     ptr  = (int*)w;     w += (size_t)N * sizeof(int);
        int*     pos  = (int*)w;     w += (size_t)E * sizeof(int);
        int*     csr  = (int*)w;     w += (size_t)E * sizeof(int);
        int*     bsum = (int*)w;     w += (size_t)1024 * sizeof(int);
        float*   dinv = (float*)w;   w += (size_t)N * sizeof(float);
        __half*  z1h  = (__half*)w;  w += (size_t)N * 16 * sizeof(__half);
        __half2* z2h  = (__half2*)w; w += (size_t)N * sizeof(__half2);
        const int NB = (N + 255) / 256;

        k_zero<<<gN, THREADS, 0, stream>>>(cnt, N);
        k_count_pos<<<gE, THREADS, 0, stream>>>(col, E, cnt, pos);
        k_scan1<<<NB, 256, 0, stream>>>(cnt, N, ptr, bsum);
        k_scan2<<<1, 1024, 0, stream>>>(bsum, NB);
        k_scan3<<<NB, 256, 0, stream>>>(ptr, bsum, N);
        k_place<<<gE, THREADS, 0, stream>>>(row, col, pos, ptr, E, csr);
        k_dinv_from_cnt<<<gN, THREADS, 0, stream>>>(cnt, dinv, N);
        k_xform1<<<gN, 256, 0, stream>>>(x, W1, dinv, z1h, N);
        k_gather1_fb<<<(N + 31) / 32, 256, 0, stream>>>(ptr, cnt, csr, z1h, dinv, b1, W2, z2h, N);
        k_gather2<<<(N + 31) / 32, 256, 0, stream>>>(ptr, cnt, csr, z2h, dinv, b2, out, N);
    }
}

// Round 16
// 187.066 us; speedup vs baseline: 1.0532x; 1.0532x over previous
//
#include <hip/hip_runtime.h>
#include <hip/hip_fp16.h>
#include <math.h>

#define THREADS 256
#define NPB 512           // nodes per bin
#define SHIFT 9
#define MASK 511
#define MAX_BINS 256
#define CAPE 20480        // per-bin capacity (mu=16.3k, +8 sigma, +3*512 align pad)
#define BIN_BLOCKS 512

// ===================== stage 1: bin edges by target>>9 (R14 proven) ==========
// Single pass: int4 stash of packed edge + bin id in LDS, LDS histogram,
// global reservation, in-LDS counting sort, wave-parallel coalesced flush.

__global__ void __launch_bounds__(256) k_bin(const int* __restrict__ row,
                                             const int* __restrict__ col,
                                             int e, int* __restrict__ binCnt,
                                             int* __restrict__ binned) {
    __shared__ int hist[MAX_BINS];
    __shared__ int cur[MAX_BINS];
    __shared__ int baseg[MAX_BINS];
    __shared__ int lofs[MAX_BINS];
    __shared__ int scn[MAX_BINS];
    extern __shared__ int dyn[];
    int per = (((e + (int)gridDim.x - 1) / (int)gridDim.x) + 3) & ~3;
    int e0 = blockIdx.x * per;
    if (e0 >= e) return;
    int e1 = min(e0 + per, e);
    int cntL = e1 - e0;
    int* sbuf  = dyn;
    int* sbuf2 = dyn + per;
    unsigned char* sbin = (unsigned char*)(dyn + 2 * per);
    int tid = threadIdx.x;
    hist[tid] = 0; cur[tid] = 0;
    __syncthreads();
    int nq = cntL >> 2;
    const int4* r4 = (const int4*)(row + e0);
    const int4* c4 = (const int4*)(col + e0);
    for (int q = tid; q < nq; q += 256) {
        int4 r = r4[q], c = c4[q];
        int b0 = c.x >> SHIFT, b1 = c.y >> SHIFT, b2 = c.z >> SHIFT, b3 = c.w >> SHIFT;
        ((int4*)sbuf)[q] = make_int4((r.x << SHIFT) | (c.x & MASK),
                                     (r.y << SHIFT) | (c.y & MASK),
                                     (r.z << SHIFT) | (c.z & MASK),
                                     (r.w << SHIFT) | (c.w & MASK));
        *((uchar4*)(sbin + q * 4)) = make_uchar4((unsigned char)b0, (unsigned char)b1,
                                                 (unsigned char)b2, (unsigned char)b3);
        atomicAdd(&hist[b0], 1); atomicAdd(&hist[b1], 1);
        atomicAdd(&hist[b2], 1); atomicAdd(&hist[b3], 1);
    }
    for (int li = (nq << 2) + tid; li < cntL; li += 256) {
        int c = col[e0 + li], r = row[e0 + li], b = c >> SHIFT;
        sbuf[li] = (r << SHIFT) | (c & MASK);
        sbin[li] = (unsigned char)b;
        atomicAdd(&hist[b], 1);
    }
    __syncthreads();
    {
        int h = hist[tid];
        baseg[tid] = (h > 0) ? atomicAdd(&binCnt[tid], h) : 0;
        scn[tid] = h;
    }
    __syncthreads();
    for (int off = 1; off < MAX_BINS; off <<= 1) {
        int a = (tid >= off) ? scn[tid - off] : 0;
        __syncthreads();
        scn[tid] += a;
        __syncthreads();
    }
    lofs[tid] = scn[tid] - hist[tid];
    __syncthreads();
    for (int li = tid; li < cntL; li += 256) {
        int b = sbin[li];
        int p = lofs[b] + atomicAdd(&cur[b], 1);
        sbuf2[p] = sbuf[li];
    }
    __syncthreads();
    int wv = tid >> 6, ln = tid & 63;
    for (int b = wv; b < MAX_BINS; b += 4) {
        int len = hist[b];
        int lo = lofs[b];
        int gb = baseg[b];
        for (int i = ln; i < len; i += 64) {
            int pos = gb + i;
            if (pos < CAPE) binned[b * CAPE + pos] = sbuf2[lo + i];
        }
    }
}

// ======= stage 2 (FUSED): per-bin counting sort -> CSR + deg + ptr + dinv ====
// + layer-1 transform z1h[node] = fp16(dinv * (x[node] @ W1)) for the bin's
// 512 nodes (R16: absorbs k_xform1 -- one fewer launch, transform FLOPs hide
// in the scatter's latency slots). Degrees padded to x4 for 16B-aligned csr.

__global__ void __launch_bounds__(512) k_sort(const int* __restrict__ binned,
                                              const int* __restrict__ binCnt,
                                              int* __restrict__ csr,
                                              int* __restrict__ gptr,
                                              int* __restrict__ gcnt,
                                              float* __restrict__ dinv,
                                              const float* __restrict__ x,
                                              const float* __restrict__ W1,
                                              __half* __restrict__ z1h, int n) {
    __shared__ int cnt[NPB];
    __shared__ int scn[NPB];
    __shared__ float sW[25 * 16];
    int b = blockIdx.x;
    int t = threadIdx.x;
    cnt[t] = 0;
    if (t < 25 * 16) sW[t] = W1[t];
    __syncthreads();
    int m = min(binCnt[b], CAPE);
    const int* eb = binned + b * CAPE;
    for (int i = t; i < m; i += 512)
        atomicAdd(&cnt[eb[i] & MASK], 1);
    __syncthreads();
    int v = cnt[t];
    int pv = (v + 3) & ~3;  // 4-aligned degree for csr segment alignment
    scn[t] = pv;
    __syncthreads();
    for (int off = 1; off < NPB; off <<= 1) {
        int a = (t >= off) ? scn[t - off] : 0;
        __syncthreads();
        scn[t] += a;
        __syncthreads();
    }
    int excl = scn[t] - pv;  // multiple of 4
    int node = b * NPB + t;
    float di = rsqrtf((float)(v + 1));
    if (node < n) {
        gptr[node] = b * CAPE + excl;
        gcnt[node] = v;
        dinv[node] = di;
    }
    cnt[t] = excl;  // reuse as cursor
    __syncthreads();
    for (int i = t; i < m; i += 512) {
        int e = eb[i];
        int slot = atomicAdd(&cnt[e & MASK], 1);
        if (slot < CAPE) csr[b * CAPE + slot] = e >> SHIFT;
    }
    // fused layer-1 transform for this bin's nodes
    if (node < n) {
        const float* xr = x + (size_t)node * 25;
        float xi[25];
#pragma unroll
        for (int k = 0; k < 25; k++) xi[k] = xr[k];
        union { int4 q[2]; __half h[16]; } u;
#pragma unroll
        for (int c = 0; c < 16; c++) {
            float a = 0.f;
#pragma unroll
            for (int k = 0; k < 25; k++) a = fmaf(xi[k], sW[k * 16 + c], a);
            u.h[c] = __float2half(a * di);
        }
        int4* o = (int4*)(z1h + (size_t)node * 16);
        o[0] = u.q[0];
        o[1] = u.q[1];
    }
}

// --- standalone xform1 (fallback path only) ----------------------------------
__global__ void __launch_bounds__(256) k_xform1(const float* __restrict__ x,
                                                const float* __restrict__ W1,
                                                const float* __restrict__ dinv,
                                                __half* __restrict__ z1h, int n) {
    __shared__ float sW[25 * 16];
    for (int t = threadIdx.x; t < 25 * 16; t += 256) sW[t] = W1[t];
    __syncthreads();
    long node = (long)blockIdx.x * 256 + threadIdx.x;
    if (node >= n) return;
    const float* xr = x + node * 25;
    float xi[25];
#pragma unroll
    for (int k = 0; k < 25; k++) xi[k] = xr[k];
    float di = dinv[node];
    union { int4 q[2]; __half h[16]; } u;
#pragma unroll
    for (int c = 0; c < 16; c++) {
        float a = 0.f;
#pragma unroll
        for (int k = 0; k < 25; k++) a = fmaf(xi[k], sW[k * 16 + c], a);
        u.h[c] = __float2half(a * di);
    }
    int4* o = (int4*)(z1h + node * 16);
    o[0] = u.q[0];
    o[1] = u.q[1];
}

// --- gather layer 1 + bias/relu + @W2: 8 lanes/node, half2 loads, ------------
// int4 csr loads (csr segments 16B-aligned by k_sort's padded scan).
__global__ void k_gather1(const int* __restrict__ ptr, const int* __restrict__ cnt,
                          const int* __restrict__ csr, const __half* __restrict__ z1h,
                          const float* __restrict__ dinv,
                          const float* __restrict__ b1, const float* __restrict__ W2,
                          __half2* __restrict__ z2h, int n) {
    int g = threadIdx.x >> 3;
    int c2 = threadIdx.x & 7;
    int node = blockIdx.x * 32 + g;
    if (node >= n) return;
    const __half2* z1p = (const __half2*)z1h;
    int beg = ptr[node], d = cnt[node];
    __half2 sv = z1p[(size_t)node * 8 + c2];
    float a0 = __low2float(sv), a1 = __high2float(sv);
    int e = 0;
    for (; e + 4 <= d; e += 4) {
        int4 s = *(const int4*)(csr + beg + e);  // aligned: beg%4==0, e%4==0
        __half2 v0 = z1p[(size_t)s.x * 8 + c2];
        __half2 v1 = z1p[(size_t)s.y * 8 + c2];
        __half2 v2 = z1p[(size_t)s.z * 8 + c2];
        __half2 v3 = z1p[(size_t)s.w * 8 + c2];
        a0 += (__low2float(v0) + __low2float(v1)) + (__low2float(v2) + __low2float(v3));
        a1 += (__high2float(v0) + __high2float(v1)) + (__high2float(v2) + __high2float(v3));
    }
    for (; e < d; e++) {
        __half2 v = z1p[(size_t)csr[beg + e] * 8 + c2];
        a0 += __low2float(v);
        a1 += __high2float(v);
    }
    float di = dinv[node];
    int cA = c2 * 2, cB = c2 * 2 + 1;
    float hA = fmaxf(fmaf(di, a0, b1[cA]), 0.f);
    float hB = fmaxf(fmaf(di, a1, b1[cB]), 0.f);
    float p0 = hA * W2[cA * 2 + 0] + hB * W2[cB * 2 + 0];
    float p1 = hA * W2[cA * 2 + 1] + hB * W2[cB * 2 + 1];
#pragma unroll
    for (int m = 1; m < 8; m <<= 1) {
        p0 += __shfl_xor(p0, m, 8);
        p1 += __shfl_xor(p1, m, 8);
    }
    if (c2 == 0) z2h[node] = __floats2half2_rn(di * p0, di * p1);
}

// --- gather layer 2: 8 lanes/node + bias + log_softmax(2) --------------------
__global__ void k_gather2(const int* __restrict__ ptr, const int* __restrict__ cnt,
                          const int* __restrict__ csr, const __half2* __restrict__ z2h,
                          const float* __restrict__ dinv,
                          const float* __restrict__ b2, float* __restrict__ out, int n) {
    int g = threadIdx.x >> 3;
    int c = threadIdx.x & 7;
    int node = blockIdx.x * 32 + g;
    if (node >= n) return;
    int beg = ptr[node], d = cnt[node];
    float a0 = 0.f, a1 = 0.f;
    for (int e = c; e < d; e += 8) {
        __half2 v = z2h[csr[beg + e]];
        a0 += __low2float(v);
        a1 += __high2float(v);
    }
#pragma unroll
    for (int m = 1; m < 8; m <<= 1) {
        a0 += __shfl_xor(a0, m, 8);
        a1 += __shfl_xor(a1, m, 8);
    }
    if (c == 0) {
        __half2 self = z2h[node];
        a0 += __low2float(self);
        a1 += __high2float(self);
        float di = dinv[node];
        float h0 = fmaf(di, a0, b2[0]);
        float h1 = fmaf(di, a1, b2[1]);
        float mx = fmaxf(h0, h1);
        float lse = mx + log1pf(expf(fminf(h0, h1) - mx));
        ((float2*)out)[node] = make_float2(h0 - lse, h1 - lse);
    }
}

// ===================== fallback: round-2 CSR pipeline ========================

__global__ void k_zero(int* cnt, int n) {
    int i = blockIdx.x * blockDim.x + threadIdx.x;
    if (i < n) cnt[i] = 0;
}

__global__ void k_count_pos(const int* __restrict__ col, int e,
                            int* __restrict__ cnt, int* __restrict__ pos) {
    int i = blockIdx.x * blockDim.x + threadIdx.x;
    if (i < e) pos[i] = atomicAdd(&cnt[col[i]], 1);
}

__global__ void k_scan1(const int* __restrict__ cnt, int n,
                        int* __restrict__ excl, int* __restrict__ bsum) {
    __shared__ int s[256];
    int i = blockIdx.x * 256 + threadIdx.x;
    int v = (i < n) ? cnt[i] : 0;
    s[threadIdx.x] = v;
    __syncthreads();
    for (int off = 1; off < 256; off <<= 1) {
        int t = (threadIdx.x >= off) ? s[threadIdx.x - off] : 0;
        __syncthreads();
        s[threadIdx.x] += t;
        __syncthreads();
    }
    if (i < n) excl[i] = s[threadIdx.x] - v;
    if (threadIdx.x == 255) bsum[blockIdx.x] = s[255];
}

__global__ void k_scan2(int* __restrict__ bsum, int nb) {
    __shared__ int s[1024];
    int v = (threadIdx.x < nb) ? bsum[threadIdx.x] : 0;
    s[threadIdx.x] = v;
    __syncthreads();
    for (int off = 1; off < 1024; off <<= 1) {
        int t = (threadIdx.x >= off) ? s[threadIdx.x - off] : 0;
        __syncthreads();
        s[threadIdx.x] += t;
        __syncthreads();
    }
    if (threadIdx.x < nb) bsum[threadIdx.x] = s[threadIdx.x] - v;
}

__global__ void k_scan3(int* __restrict__ excl, const int* __restrict__ boff, int n) {
    int i = blockIdx.x * 256 + threadIdx.x;
    if (i < n) excl[i] += boff[blockIdx.x];
}

__global__ void k_place(const int* __restrict__ row, const int* __restrict__ col,
                        const int* __restrict__ pos, const int* __restrict__ ptr,
                        int e, int* __restrict__ csr) {
    int i = blockIdx.x * blockDim.x + threadIdx.x;
    if (i >= e) return;
    csr[ptr[col[i]] + pos[i]] = row[i];
}

__global__ void k_dinv_from_cnt(const int* __restrict__ cnt, float* __restrict__ dinv, int n) {
    int i = blockIdx.x * blockDim.x + threadIdx.x;
    if (i < n) dinv[i] = rsqrtf((float)(cnt[i] + 1));
}

__global__ void k_gather1_fb(const int* __restrict__ ptr, const int* __restrict__ cnt,
                             const int* __restrict__ csr, const __half* __restrict__ z1h,
                             const float* __restrict__ dinv,
                             const float* __restrict__ b1, const float* __restrict__ W2,
                             __half2* __restrict__ z2h, int n) {
    int g = threadIdx.x >> 3;
    int c2 = threadIdx.x & 7;
    int node = blockIdx.x * 32 + g;
    if (node >= n) return;
    const __half2* z1p = (const __half2*)z1h;
    int beg = ptr[node], d = cnt[node];
    __half2 sv = z1p[(size_t)node * 8 + c2];
    float a0 = __low2float(sv), a1 = __high2float(sv);
    for (int e = 0; e < d; e++) {
        __half2 v = z1p[(size_t)csr[beg + e] * 8 + c2];
        a0 += __low2float(v);
        a1 += __high2float(v);
    }
    float di = dinv[node];
    int cA = c2 * 2, cB = c2 * 2 + 1;
    float hA = fmaxf(fmaf(di, a0, b1[cA]), 0.f);
    float hB = fmaxf(fmaf(di, a1, b1[cB]), 0.f);
    float p0 = hA * W2[cA * 2 + 0] + hB * W2[cB * 2 + 0];
    float p1 = hA * W2[cA * 2 + 1] + hB * W2[cB * 2 + 1];
#pragma unroll
    for (int m = 1; m < 8; m <<= 1) {
        p0 += __shfl_xor(p0, m, 8);
        p1 += __shfl_xor(p1, m, 8);
    }
    if (c2 == 0) z2h[node] = __floats2half2_rn(di * p0, di * p1);
}

// ============================== host launcher ================================

extern "C" void kernel_launch(void* const* d_in, const int* in_sizes, int n_in,
                              void* d_out, int out_size, void* d_ws, size_t ws_size,
                              hipStream_t stream) {
    const float* x  = (const float*)d_in[0];
    const int*   ei = (const int*)d_in[1];
    const float* W1 = (const float*)d_in[2];
    const float* b1 = (const float*)d_in[3];
    const float* W2 = (const float*)d_in[4];
    const float* b2 = (const float*)d_in[5];
    float* out = (float*)d_out;

    const int N = in_sizes[0] / 25;
    const int E = in_sizes[1] / 2;
    const int* row = ei;
    const int* col = ei + E;

    const int nbins = (N + NPB - 1) / NPB;
    const int gN = (N + THREADS - 1) / THREADS;
    const int gE = (E + THREADS - 1) / THREADS;

    size_t off = 0;
    auto take = [&](size_t bytes) { size_t o = off; off = (off + bytes + 255) & ~(size_t)255; return o; };
    size_t o_binCnt = take(MAX_BINS * sizeof(int));
    size_t o_binned = take((size_t)nbins * CAPE * sizeof(int));
    size_t o_csr    = take((size_t)nbins * CAPE * sizeof(int));
    size_t o_ptr    = take((size_t)N * sizeof(int));
    size_t o_cnt    = take((size_t)N * sizeof(int));
    size_t o_dinv   = take((size_t)N * sizeof(float));
    size_t o_z1h    = take((size_t)N * 16 * sizeof(__half));
    size_t o_z2h    = take((size_t)N * sizeof(__half2));
    size_t need_v16 = off;

    // bin load: mu = E/nbins, sigma = sqrt(mu); csr needs +3*NPB alignment pad
    double mu = (double)E / (double)nbins;
    bool cap_ok = (mu + 8.0 * sqrt(mu) + 3.0 * NPB) < (double)CAPE;
    const int per = (((E + BIN_BLOCKS - 1) / BIN_BLOCKS) + 3) & ~3;
    size_t dynLds = (size_t)per * 9 + 64;  // sbuf + sbuf2 (4B) + sbin (1B)
    bool lds_ok = dynLds <= 60 * 1024;
    bool use_v16 = (nbins <= MAX_BINS) && (ws_size >= need_v16) &&
                   (N <= NPB * MAX_BINS) && cap_ok && lds_ok;

    char* wsb = (char*)d_ws;
    if (use_v16) {
        int*     binCnt = (int*)(wsb + o_binCnt);
        int*     binned = (int*)(wsb + o_binned);
        int*     csr    = (int*)(wsb + o_csr);
        int*     ptr    = (int*)(wsb + o_ptr);
        int*     cnt    = (int*)(wsb + o_cnt);
        float*   dinv   = (float*)(wsb + o_dinv);
        __half*  z1h    = (__half*)(wsb + o_z1h);
        __half2* z2h    = (__half2*)(wsb + o_z2h);

        hipMemsetAsync(binCnt, 0, MAX_BINS * sizeof(int), stream);
        k_bin<<<BIN_BLOCKS, 256, dynLds, stream>>>(row, col, E, binCnt, binned);
        k_sort<<<nbins, 512, 0, stream>>>(binned, binCnt, csr, ptr, cnt, dinv, x, W1, z1h, N);
        k_gather1<<<(N + 31) / 32, 256, 0, stream>>>(ptr, cnt, csr, z1h, dinv, b1, W2, z2h, N);
        k_gather2<<<(N + 31) / 32, 256, 0, stream>>>(ptr, cnt, csr, z2h, dinv, b2, out, N);
    } else {
        char* w = wsb;
        int*     cnt  = (int*)w;     w += (size_t)N * sizeof(int);
        int*     ptr  = (int*)w;     w += (size_t)N * sizeof(int);
        int*     pos  = (int*)w;     w += (size_t)E * sizeof(int);
        int*     csr  = (int*)w;     w += (size_t)E * sizeof(int);
        int*     bsum = (int*)w;     w += (size_t)1024 * sizeof(int);
        float*   dinv = (float*)w;   w += (size_t)N * sizeof(float);
        __half*  z1h  = (__half*)w;  w += (size_t)N * 16 * sizeof(__half);
        __half2* z2h  = (__half2*)w; w += (size_t)N * sizeof(__half2);
        const int NB = (N + 255) / 256;

        k_zero<<<gN, THREADS, 0, stream>>>(cnt, N);
        k_count_pos<<<gE, THREADS, 0, stream>>>(col, E, cnt, pos);
        k_scan1<<<NB, 256, 0, stream>>>(cnt, N, ptr, bsum);
        k_scan2<<<1, 1024, 0, stream>>>(bsum, NB);
        k_scan3<<<NB, 256, 0, stream>>>(ptr, bsum, N);
        k_place<<<gE, THREADS, 0, stream>>>(row, col, pos, ptr, E, csr);
        k_dinv_from_cnt<<<gN, THREADS, 0, stream>>>(cnt, dinv, N);
        k_xform1<<<gN, 256, 0, stream>>>(x, W1, dinv, z1h, N);
        k_gather1_fb<<<(N + 31) / 32, 256, 0, stream>>>(ptr, cnt, csr, z1h, dinv, b1, W2, z2h, N);
        k_gather2<<<(N + 31) / 32, 256, 0, stream>>>(ptr, cnt, csr, z2h, dinv, b2, out, N);
    }
}

// Round 17
// 186.664 us; speedup vs baseline: 1.0555x; 1.0022x over previous
//
#include <hip/hip_runtime.h>
#include <hip/hip_fp16.h>
#include <math.h>

#define THREADS 256
#define NPB 512           // nodes per bin
#define SHIFT 9
#define MASK 511
#define MAX_BINS 256
#define CAPE 20480        // per-bin capacity (mu=16.3k, +8 sigma, +3*512 pad)
#define BIN_BLOCKS 512
#define SENT (-1)         // sentinel for pad slots (valid packed edges < 2^31)

// ===================== stage 1: bin edges by target>>9 =======================
// R17: reservations padded to x4 (16B-aligned bases), pass C flushes int4
// chunks (4x fewer stores, aligned) with SENT in pad slots.

__global__ void __launch_bounds__(256) k_bin(const int* __restrict__ row,
                                             const int* __restrict__ col,
                                             int e, int* __restrict__ binCnt,
                                             int* __restrict__ binned) {
    __shared__ int hist[MAX_BINS];
    __shared__ int cur[MAX_BINS];
    __shared__ int baseg[MAX_BINS];
    __shared__ int lofs[MAX_BINS];
    __shared__ int scn[MAX_BINS];
    extern __shared__ int dyn[];
    int per = (((e + (int)gridDim.x - 1) / (int)gridDim.x) + 3) & ~3;
    int e0 = blockIdx.x * per;
    if (e0 >= e) return;
    int e1 = min(e0 + per, e);
    int cntL = e1 - e0;
    int* sbuf  = dyn;
    int* sbuf2 = dyn + per;
    unsigned char* sbin = (unsigned char*)(dyn + 2 * per);
    int tid = threadIdx.x;
    hist[tid] = 0; cur[tid] = 0;
    __syncthreads();
    int nq = cntL >> 2;
    const int4* r4 = (const int4*)(row + e0);
    const int4* c4 = (const int4*)(col + e0);
    for (int q = tid; q < nq; q += 256) {
        int4 r = r4[q], c = c4[q];
        int b0 = c.x >> SHIFT, b1 = c.y >> SHIFT, b2 = c.z >> SHIFT, b3 = c.w >> SHIFT;
        ((int4*)sbuf)[q] = make_int4((r.x << SHIFT) | (c.x & MASK),
                                     (r.y << SHIFT) | (c.y & MASK),
                                     (r.z << SHIFT) | (c.z & MASK),
                                     (r.w << SHIFT) | (c.w & MASK));
        *((uchar4*)(sbin + q * 4)) = make_uchar4((unsigned char)b0, (unsigned char)b1,
                                                 (unsigned char)b2, (unsigned char)b3);
        atomicAdd(&hist[b0], 1); atomicAdd(&hist[b1], 1);
        atomicAdd(&hist[b2], 1); atomicAdd(&hist[b3], 1);
    }
    for (int li = (nq << 2) + tid; li < cntL; li += 256) {
        int c = col[e0 + li], r = row[e0 + li], b = c >> SHIFT;
        sbuf[li] = (r << SHIFT) | (c & MASK);
        sbin[li] = (unsigned char)b;
        atomicAdd(&hist[b], 1);
    }
    __syncthreads();
    {
        int h = hist[tid];
        baseg[tid] = (h > 0) ? atomicAdd(&binCnt[tid], (h + 3) & ~3) : 0;  // x4 pad
        scn[tid] = h;
    }
    __syncthreads();
    for (int off = 1; off < MAX_BINS; off <<= 1) {
        int a = (tid >= off) ? scn[tid - off] : 0;
        __syncthreads();
        scn[tid] += a;
        __syncthreads();
    }
    lofs[tid] = scn[tid] - hist[tid];
    __syncthreads();
    for (int li = tid; li < cntL; li += 256) {
        int b = sbin[li];
        int p = lofs[b] + atomicAdd(&cur[b], 1);
        sbuf2[p] = sbuf[li];
    }
    __syncthreads();
    // pass C: wave-per-bin flush, int4 chunks (baseg multiple of 4)
    int wv = tid >> 6, ln = tid & 63;
    for (int b = wv; b < MAX_BINS; b += 4) {
        int len = hist[b];
        if (len == 0) continue;
        int lo = lofs[b];
        int gb = baseg[b];
        int n4 = (len + 3) >> 2;
        for (int i4 = ln; i4 < n4; i4 += 64) {
            int base = i4 * 4;
            int4 v;
            v.x = (base + 0 < len) ? sbuf2[lo + base + 0] : SENT;
            v.y = (base + 1 < len) ? sbuf2[lo + base + 1] : SENT;
            v.z = (base + 2 < len) ? sbuf2[lo + base + 2] : SENT;
            v.w = (base + 3 < len) ? sbuf2[lo + base + 3] : SENT;
            int pos = gb + base;
            if (pos + 4 <= CAPE) *(int4*)(binned + b * CAPE + pos) = v;
        }
    }
}

// ======= stage 2 (FUSED): per-bin counting sort -> CSR + deg + dinv ==========
// + layer-1 transform (R16-proven). Int4 reads of binned, sentinel-skipping.

__global__ void __launch_bounds__(512) k_sort(const int* __restrict__ binned,
                                              const int* __restrict__ binCnt,
                                              int* __restrict__ csr,
                                              int* __restrict__ gptr,
                                              int* __restrict__ gcnt,
                                              float* __restrict__ dinv,
                                              const float* __restrict__ x,
                                              const float* __restrict__ W1,
                                              __half* __restrict__ z1h, int n) {
    __shared__ int cnt[NPB];
    __shared__ int scn[NPB];
    __shared__ float sW[25 * 16];
    int b = blockIdx.x;
    int t = threadIdx.x;
    cnt[t] = 0;
    if (t < 25 * 16) sW[t] = W1[t];
    __syncthreads();
    int m = min(binCnt[b], CAPE);   // multiple of 4 (padded reservations)
    int m4 = m >> 2;
    const int4* eb4 = (const int4*)(binned + b * CAPE);
    for (int i = t; i < m4; i += 512) {
        int4 v = eb4[i];
        if (v.x != SENT) atomicAdd(&cnt[v.x & MASK], 1);
        if (v.y != SENT) atomicAdd(&cnt[v.y & MASK], 1);
        if (v.z != SENT) atomicAdd(&cnt[v.z & MASK], 1);
        if (v.w != SENT) atomicAdd(&cnt[v.w & MASK], 1);
    }
    __syncthreads();
    int v = cnt[t];
    int pv = (v + 3) & ~3;  // 4-aligned degree for csr segment alignment
    scn[t] = pv;
    __syncthreads();
    for (int off = 1; off < NPB; off <<= 1) {
        int a = (t >= off) ? scn[t - off] : 0;
        __syncthreads();
        scn[t] += a;
        __syncthreads();
    }
    int excl = scn[t] - pv;  // multiple of 4
    int node = b * NPB + t;
    float di = rsqrtf((float)(v + 1));
    if (node < n) {
        gptr[node] = b * CAPE + excl;
        gcnt[node] = v;
        dinv[node] = di;
    }
    cnt[t] = excl;  // reuse as cursor
    __syncthreads();
    for (int i = t; i < m4; i += 512) {
        int4 q = eb4[i];
        int e, slot;
        e = q.x; if (e != SENT) { slot = atomicAdd(&cnt[e & MASK], 1); if (slot < CAPE) csr[b * CAPE + slot] = e >> SHIFT; }
        e = q.y; if (e != SENT) { slot = atomicAdd(&cnt[e & MASK], 1); if (slot < CAPE) csr[b * CAPE + slot] = e >> SHIFT; }
        e = q.z; if (e != SENT) { slot = atomicAdd(&cnt[e & MASK], 1); if (slot < CAPE) csr[b * CAPE + slot] = e >> SHIFT; }
        e = q.w; if (e != SENT) { slot = atomicAdd(&cnt[e & MASK], 1); if (slot < CAPE) csr[b * CAPE + slot] = e >> SHIFT; }
    }
    // fused layer-1 transform for this bin's nodes
    if (node < n) {
        const float* xr = x + (size_t)node * 25;
        float xi[25];
#pragma unroll
        for (int k = 0; k < 25; k++) xi[k] = xr[k];
        union { int4 q[2]; __half h[16]; } u;
#pragma unroll
        for (int c = 0; c < 16; c++) {
            float a = 0.f;
#pragma unroll
            for (int k = 0; k < 25; k++) a = fmaf(xi[k], sW[k * 16 + c], a);
            u.h[c] = __float2half(a * di);
        }
        int4* o = (int4*)(z1h + (size_t)node * 16);
        o[0] = u.q[0];
        o[1] = u.q[1];
    }
}

// --- standalone xform1 (fallback path only) ----------------------------------
__global__ void __launch_bounds__(256) k_xform1(const float* __restrict__ x,
                                                const float* __restrict__ W1,
                                                const float* __restrict__ dinv,
                                                __half* __restrict__ z1h, int n) {
    __shared__ float sW[25 * 16];
    for (int t = threadIdx.x; t < 25 * 16; t += 256) sW[t] = W1[t];
    __syncthreads();
    long node = (long)blockIdx.x * 256 + threadIdx.x;
    if (node >= n) return;
    const float* xr = x + node * 25;
    float xi[25];
#pragma unroll
    for (int k = 0; k < 25; k++) xi[k] = xr[k];
    float di = dinv[node];
    union { int4 q[2]; __half h[16]; } u;
#pragma unroll
    for (int c = 0; c < 16; c++) {
        float a = 0.f;
#pragma unroll
        for (int k = 0; k < 25; k++) a = fmaf(xi[k], sW[k * 16 + c], a);
        u.h[c] = __float2half(a * di);
    }
    int4* o = (int4*)(z1h + node * 16);
    o[0] = u.q[0];
    o[1] = u.q[1];
}

// --- gather layer 1 + bias/relu + @W2: 8 lanes/node, half2 loads, ------------
// int4 csr loads (csr segments 16B-aligned by k_sort's padded scan).
__global__ void k_gather1(const int* __restrict__ ptr, const int* __restrict__ cnt,
                          const int* __restrict__ csr, const __half* __restrict__ z1h,
                          const float* __restrict__ dinv,
                          const float* __restrict__ b1, const float* __restrict__ W2,
                          __half2* __restrict__ z2h, int n) {
    int g = threadIdx.x >> 3;
    int c2 = threadIdx.x & 7;
    int node = blockIdx.x * 32 + g;
    if (node >= n) return;
    const __half2* z1p = (const __half2*)z1h;
    int beg = ptr[node], d = cnt[node];
    __half2 sv = z1p[(size_t)node * 8 + c2];
    float a0 = __low2float(sv), a1 = __high2float(sv);
    int e = 0;
    for (; e + 4 <= d; e += 4) {
        int4 s = *(const int4*)(csr + beg + e);  // aligned: beg%4==0, e%4==0
        __half2 v0 = z1p[(size_t)s.x * 8 + c2];
        __half2 v1 = z1p[(size_t)s.y * 8 + c2];
        __half2 v2 = z1p[(size_t)s.z * 8 + c2];
        __half2 v3 = z1p[(size_t)s.w * 8 + c2];
        a0 += (__low2float(v0) + __low2float(v1)) + (__low2float(v2) + __low2float(v3));
        a1 += (__high2float(v0) + __high2float(v1)) + (__high2float(v2) + __high2float(v3));
    }
    for (; e < d; e++) {
        __half2 v = z1p[(size_t)csr[beg + e] * 8 + c2];
        a0 += __low2float(v);
        a1 += __high2float(v);
    }
    float di = dinv[node];
    int cA = c2 * 2, cB = c2 * 2 + 1;
    float hA = fmaxf(fmaf(di, a0, b1[cA]), 0.f);
    float hB = fmaxf(fmaf(di, a1, b1[cB]), 0.f);
    float p0 = hA * W2[cA * 2 + 0] + hB * W2[cB * 2 + 0];
    float p1 = hA * W2[cA * 2 + 1] + hB * W2[cB * 2 + 1];
#pragma unroll
    for (int m = 1; m < 8; m <<= 1) {
        p0 += __shfl_xor(p0, m, 8);
        p1 += __shfl_xor(p1, m, 8);
    }
    if (c2 == 0) z2h[node] = __floats2half2_rn(di * p0, di * p1);
}

// --- gather layer 2: 8 lanes/node + bias + log_softmax(2) --------------------
__global__ void k_gather2(const int* __restrict__ ptr, const int* __restrict__ cnt,
                          const int* __restrict__ csr, const __half2* __restrict__ z2h,
                          const float* __restrict__ dinv,
                          const float* __restrict__ b2, float* __restrict__ out, int n) {
    int g = threadIdx.x >> 3;
    int c = threadIdx.x & 7;
    int node = blockIdx.x * 32 + g;
    if (node >= n) return;
    int beg = ptr[node], d = cnt[node];
    float a0 = 0.f, a1 = 0.f;
    for (int e = c; e < d; e += 8) {
        __half2 v = z2h[csr[beg + e]];
        a0 += __low2float(v);
        a1 += __high2float(v);
    }
#pragma unroll
    for (int m = 1; m < 8; m <<= 1) {
        a0 += __shfl_xor(a0, m, 8);
        a1 += __shfl_xor(a1, m, 8);
    }
    if (c == 0) {
        __half2 self = z2h[node];
        a0 += __low2float(self);
        a1 += __high2float(self);
        float di = dinv[node];
        float h0 = fmaf(di, a0, b2[0]);
        float h1 = fmaf(di, a1, b2[1]);
        float mx = fmaxf(h0, h1);
        float lse = mx + log1pf(expf(fminf(h0, h1) - mx));
        ((float2*)out)[node] = make_float2(h0 - lse, h1 - lse);
    }
}

// ===================== fallback: round-2 CSR pipeline ========================

__global__ void k_zero(int* cnt, int n) {
    int i = blockIdx.x * blockDim.x + threadIdx.x;
    if (i < n) cnt[i] = 0;
}

__global__ void k_count_pos(const int* __restrict__ col, int e,
                            int* __restrict__ cnt, int* __restrict__ pos) {
    int i = blockIdx.x * blockDim.x + threadIdx.x;
    if (i < e) pos[i] = atomicAdd(&cnt[col[i]], 1);
}

__global__ void k_scan1(const int* __restrict__ cnt, int n,
                        int* __restrict__ excl, int* __restrict__ bsum) {
    __shared__ int s[256];
    int i = blockIdx.x * 256 + threadIdx.x;
    int v = (i < n) ? cnt[i] : 0;
    s[threadIdx.x] = v;
    __syncthreads();
    for (int off = 1; off < 256; off <<= 1) {
        int t = (threadIdx.x >= off) ? s[threadIdx.x - off] : 0;
        __syncthreads();
        s[threadIdx.x] += t;
        __syncthreads();
    }
    if (i < n) excl[i] = s[threadIdx.x] - v;
    if (threadIdx.x == 255) bsum[blockIdx.x] = s[255];
}

__global__ void k_scan2(int* __restrict__ bsum, int nb) {
    __shared__ int s[1024];
    int v = (threadIdx.x < nb) ? bsum[threadIdx.x] : 0;
    s[threadIdx.x] = v;
    __syncthreads();
    for (int off = 1; off < 1024; off <<= 1) {
        int t = (threadIdx.x >= off) ? s[threadIdx.x - off] : 0;
        __syncthreads();
        s[threadIdx.x] += t;
        __syncthreads();
    }
    if (threadIdx.x < nb) bsum[threadIdx.x] = s[threadIdx.x] - v;
}

__global__ void k_scan3(int* __restrict__ excl, const int* __restrict__ boff, int n) {
    int i = blockIdx.x * 256 + threadIdx.x;
    if (i < n) excl[i] += boff[blockIdx.x];
}

__global__ void k_place(const int* __restrict__ row, const int* __restrict__ col,
                        const int* __restrict__ pos, const int* __restrict__ ptr,
                        int e, int* __restrict__ csr) {
    int i = blockIdx.x * blockDim.x + threadIdx.x;
    if (i >= e) return;
    csr[ptr[col[i]] + pos[i]] = row[i];
}

__global__ void k_dinv_from_cnt(const int* __restrict__ cnt, float* __restrict__ dinv, int n) {
    int i = blockIdx.x * blockDim.x + threadIdx.x;
    if (i < n) dinv[i] = rsqrtf((float)(cnt[i] + 1));
}

__global__ void k_gather1_fb(const int* __restrict__ ptr, const int* __restrict__ cnt,
                             const int* __restrict__ csr, const __half* __restrict__ z1h,
                             const float* __restrict__ dinv,
                             const float* __restrict__ b1, const float* __restrict__ W2,
                             __half2* __restrict__ z2h, int n) {
    int g = threadIdx.x >> 3;
    int c2 = threadIdx.x & 7;
    int node = blockIdx.x * 32 + g;
    if (node >= n) return;
    const __half2* z1p = (const __half2*)z1h;
    int beg = ptr[node], d = cnt[node];
    __half2 sv = z1p[(size_t)node * 8 + c2];
    float a0 = __low2float(sv), a1 = __high2float(sv);
    for (int e = 0; e < d; e++) {
        __half2 v = z1p[(size_t)csr[beg + e] * 8 + c2];
        a0 += __low2float(v);
        a1 += __high2float(v);
    }
    float di = dinv[node];
    int cA = c2 * 2, cB = c2 * 2 + 1;
    float hA = fmaxf(fmaf(di, a0, b1[cA]), 0.f);
    float hB = fmaxf(fmaf(di, a1, b1[cB]), 0.f);
    float p0 = hA * W2[cA * 2 + 0] + hB * W2[cB * 2 + 0];
    float p1 = hA * W2[cA * 2 + 1] + hB * W2[cB * 2 + 1];
#pragma unroll
    for (int m = 1; m < 8; m <<= 1) {
        p0 += __shfl_xor(p0, m, 8);
        p1 += __shfl_xor(p1, m, 8);
    }
    if (c2 == 0) z2h[node] = __floats2half2_rn(di * p0, di * p1);
}

// ============================== host launcher ================================

extern "C" void kernel_launch(void* const* d_in, const int* in_sizes, int n_in,
                              void* d_out, int out_size, void* d_ws, size_t ws_size,
                              hipStream_t stream) {
    const float* x  = (const float*)d_in[0];
    const int*   ei = (const int*)d_in[1];
    const float* W1 = (const float*)d_in[2];
    const float* b1 = (const float*)d_in[3];
    const float* W2 = (const float*)d_in[4];
    const float* b2 = (const float*)d_in[5];
    float* out = (float*)d_out;

    const int N = in_sizes[0] / 25;
    const int E = in_sizes[1] / 2;
    const int* row = ei;
    const int* col = ei + E;

    const int nbins = (N + NPB - 1) / NPB;
    const int gN = (N + THREADS - 1) / THREADS;
    const int gE = (E + THREADS - 1) / THREADS;

    size_t off = 0;
    auto take = [&](size_t bytes) { size_t o = off; off = (off + bytes + 255) & ~(size_t)255; return o; };
    size_t o_binCnt = take(MAX_BINS * sizeof(int));
    size_t o_binned = take((size_t)nbins * CAPE * sizeof(int));
    size_t o_csr    = take((size_t)nbins * CAPE * sizeof(int));
    size_t o_ptr    = take((size_t)N * sizeof(int));
    size_t o_cnt    = take((size_t)N * sizeof(int));
    size_t o_dinv   = take((size_t)N * sizeof(float));
    size_t o_z1h    = take((size_t)N * 16 * sizeof(__half));
    size_t o_z2h    = take((size_t)N * sizeof(__half2));
    size_t need_v17 = off;

    // bin load: mu + 8*sigma + 3*NPB pad (covers both x4 reservation pad and
    // csr alignment pad, each bounded by 3*BIN_BLOCKS=1536=3*NPB)
    double mu = (double)E / (double)nbins;
    bool cap_ok = (mu + 8.0 * sqrt(mu) + 3.0 * NPB) < (double)CAPE;
    const int per = (((E + BIN_BLOCKS - 1) / BIN_BLOCKS) + 3) & ~3;
    size_t dynLds = (size_t)per * 9 + 64;  // sbuf + sbuf2 (4B) + sbin (1B)
    bool lds_ok = dynLds <= 60 * 1024;
    bool use_v17 = (nbins <= MAX_BINS) && (ws_size >= need_v17) &&
                   (N <= NPB * MAX_BINS) && cap_ok && lds_ok &&
                   (3 * BIN_BLOCKS <= 3 * NPB);

    char* wsb = (char*)d_ws;
    if (use_v17) {
        int*     binCnt = (int*)(wsb + o_binCnt);
        int*     binned = (int*)(wsb + o_binned);
        int*     csr    = (int*)(wsb + o_csr);
        int*     ptr    = (int*)(wsb + o_ptr);
        int*     cnt    = (int*)(wsb + o_cnt);
        float*   dinv   = (float*)(wsb + o_dinv);
        __half*  z1h    = (__half*)(wsb + o_z1h);
        __half2* z2h    = (__half2*)(wsb + o_z2h);

        hipMemsetAsync(binCnt, 0, MAX_BINS * sizeof(int), stream);
        k_bin<<<BIN_BLOCKS, 256, dynLds, stream>>>(row, col, E, binCnt, binned);
        k_sort<<<nbins, 512, 0, stream>>>(binned, binCnt, csr, ptr, cnt, dinv, x, W1, z1h, N);
        k_gather1<<<(N + 31) / 32, 256, 0, stream>>>(ptr, cnt, csr, z1h, dinv, b1, W2, z2h, N);
        k_gather2<<<(N + 31) / 32, 256, 0, stream>>>(ptr, cnt, csr, z2h, dinv, b2, out, N);
    } else {
        char* w = wsb;
        int*     cnt  = (int*)w;     w += (size_t)N * sizeof(int);
        int*     ptr  = (int*)w;     w += (size_t)N * sizeof(int);
        int*     pos  = (int*)w;     w += (size_t)E * sizeof(int);
        int*     csr  = (int*)w;     w += (size_t)E * sizeof(int);
        int*     bsum = (int*)w;     w += (size_t)1024 * sizeof(int);
        float*   dinv = (float*)w;   w += (size_t)N * sizeof(float);
        __half*  z1h  = (__half*)w;  w += (size_t)N * 16 * sizeof(__half);
        __half2* z2h  = (__half2*)w; w += (size_t)N * sizeof(__half2);
        const int NB = (N + 255) / 256;

        k_zero<<<gN, THREADS, 0, stream>>>(cnt, N);
        k_count_pos<<<gE, THREADS, 0, stream>>>(col, E, cnt, pos);
        k_scan1<<<NB, 256, 0, stream>>>(cnt, N, ptr, bsum);
        k_scan2<<<1, 1024, 0, stream>>>(bsum, NB);
        k_scan3<<<NB, 256, 0, stream>>>(ptr, bsum, N);
        k_place<<<gE, THREADS, 0, stream>>>(row, col, pos, ptr, E, csr);
        k_dinv_from_cnt<<<gN, THREADS, 0, stream>>>(cnt, dinv, N);
        k_xform1<<<gN, 256, 0, stream>>>(x, W1, dinv, z1h, N);
        k_gather1_fb<<<(N + 31) / 32, 256, 0, stream>>>(ptr, cnt, csr, z1h, dinv, b1, W2, z2h, N);
        k_gather2<<<(N + 31) / 32, 256, 0, stream>>>(ptr, cnt, csr, z2h, dinv, b2, out, N);
    }
}